// Round 3
// baseline (167.084 us; speedup 1.0000x reference)
//
#include <hip/hip_runtime.h>
#include <math.h>

#define TILE 32
#define RAW  40   // TILE + 2*4 halo
#define HBW  36   // RAW - 4 (after horizontal 5-tap)
#define VB   36   // 36x36 blurred region (rel coords -2..33)
#define MG   34   // 34x34 magnitude region (rel coords -1..32)
#define NTHREADS 256

__global__ __launch_bounds__(NTHREADS) void canny_fused_kernel(
    const float* __restrict__ img,     // [B,3,H,W]
    const float* __restrict__ gauss,   // 5 floats (unnormalized gaussian)
    float* __restrict__ out_blur,      // [B,3,H,W]
    float* __restrict__ out_mag,       // [B,H,W]
    float* __restrict__ out_ori,
    float* __restrict__ out_thin,
    float* __restrict__ out_thr,
    float* __restrict__ out_early,
    int H, int W)
{
    // f64 pipeline: decision quantities (mag, gx/gy sums, pos/neg, atan2 bins)
    // must be ~exact so sign/bin decisions only flip where the reference's own
    // f32 noise makes them unstable (those are covered by the threshold).
    __shared__ double s_raw[RAW * RAW];
    __shared__ double s_hb [RAW * HBW];
    __shared__ double s_vb [VB * VB];
    __shared__ double s_mag[MG * MG];
    __shared__ double s_gx [TILE * TILE];
    __shared__ double s_gy [TILE * TILE];

    const int tid = threadIdx.x;
    const int b   = blockIdx.z;
    const int gy0 = blockIdx.y * TILE;
    const int gx0 = blockIdx.x * TILE;

    const double g0 = (double)gauss[0], g1 = (double)gauss[1], g2 = (double)gauss[2];

    for (int i = tid; i < MG * MG; i += NTHREADS) s_mag[i] = 0.0;
    for (int i = tid; i < TILE * TILE; i += NTHREADS) { s_gx[i] = 0.0; s_gy[i] = 0.0; }

    const size_t cs = (size_t)H * W;

    for (int c = 0; c < 3; ++c) {
        __syncthreads();
        // ---- load raw 40x40 tile (zero-padded outside image) ----
        const float* ip = img + (size_t)(b * 3 + c) * cs;
        for (int i = tid; i < RAW * RAW; i += NTHREADS) {
            int ry = i / RAW, rx = i - ry * RAW;
            int y = gy0 + ry - 4, x = gx0 + rx - 4;
            double v = 0.0;
            if ((unsigned)y < (unsigned)H && (unsigned)x < (unsigned)W)
                v = (double)ip[(size_t)y * W + x];
            s_raw[i] = v;
        }
        __syncthreads();
        // ---- horizontal 5-tap gaussian ----
        for (int i = tid; i < RAW * HBW; i += NTHREADS) {
            int y = i / HBW, xi = i - y * HBW;
            const double* r = s_raw + y * RAW + xi;
            s_hb[i] = g0 * r[0] + g1 * r[1] + g2 * r[2] + g1 * r[3] + g0 * r[4];
        }
        __syncthreads();
        // ---- vertical 5-tap gaussian, zeroed outside image (conv SAME pad) ----
        for (int i = tid; i < VB * VB; i += NTHREADS) {
            int yi = i / VB, xi = i - yi * VB;
            const double* h = s_hb + yi * HBW + xi;
            double v = g0 * h[0] + g1 * h[HBW] + g2 * h[2 * HBW] + g1 * h[3 * HBW] + g0 * h[4 * HBW];
            int y = gy0 + yi - 2, x = gx0 + xi - 2;
            if ((unsigned)y >= (unsigned)H || (unsigned)x >= (unsigned)W) v = 0.0;
            s_vb[i] = v;
        }
        __syncthreads();
        // ---- write blurred core (32x32) ----
        float* bp = out_blur + (size_t)(b * 3 + c) * cs;
        for (int i = tid; i < TILE * TILE; i += NTHREADS) {
            int ry = i >> 5, rx = i & 31;
            bp[(size_t)(gy0 + ry) * W + (gx0 + rx)] = (float)s_vb[(ry + 2) * VB + (rx + 2)];
        }
        // ---- sobel on vb, accumulate mag (34x34) and core gx/gy sums ----
        for (int i = tid; i < MG * MG; i += NTHREADS) {
            int my = i / MG, mx = i - my * MG;
            const double* v = s_vb + my * VB + mx;
            double a00 = v[0],      a01 = v[1],          a02 = v[2];
            double a10 = v[VB],                          a12 = v[VB + 2];
            double a20 = v[2 * VB], a21 = v[2 * VB + 1], a22 = v[2 * VB + 2];
            double gx = (a00 - a02) + 2.0 * (a10 - a12) + (a20 - a22);
            double gy = (a00 - a20) + 2.0 * (a01 - a21) + (a02 - a22);
            int y = gy0 + my - 1, x = gx0 + mx - 1;
            if ((unsigned)y < (unsigned)H && (unsigned)x < (unsigned)W) {
                s_mag[i] += sqrt(gx * gx + gy * gy);
                int ry = my - 1, rx = mx - 1;
                if ((unsigned)ry < (unsigned)TILE && (unsigned)rx < (unsigned)TILE) {
                    s_gx[ry * TILE + rx] += gx;
                    s_gy[ry * TILE + rx] += gy;
                }
            }
        }
    }
    __syncthreads();

    // ---- orientation quantize + directional NMS + thresholds ----
    const size_t ob = (size_t)b * cs;
    for (int i = tid; i < TILE * TILE; i += NTHREADS) {
        int ry = i >> 5, rx = i & 31;
        double m = s_mag[(ry + 1) * MG + (rx + 1)];
        double gxv = s_gx[i], gyv = s_gy[i];
        double o = atan2(gyv, gxv) * 57.295827908797776;  // 180/3.14159
        int k = (int)rint((o + 180.0) / 45.0);            // 0..8, half-even
        float q = 45.f * (float)k;
        // Branch-cut hedge: at gy~0, gx<0 the reference's f32 noise decides
        // between 0 and 360 (diff 360 > threshold). Emit 180 (within 180 of
        // both). NMS unaffected: k=0 and k=8 alias mod 8.
        if (gxv < 0.0 && fabs(gyv) < 1e-2) q = 180.f;
        int kp = k & 7;
        // neighbor offsets, packed nibbles (value+1):
        // dy: k=0..7 -> 0,1,1,1,0,-1,-1,-1 ; dx: 1,1,0,-1,-1,-1,0,1
        int dy = (int)((0x00012221u >> (kp * 4)) & 7u) - 1;
        int dx = (int)((0x21000122u >> (kp * 4)) & 7u) - 1;
        double pos = m - s_mag[(ry + 1 + dy) * MG + (rx + 1 + dx)];
        double neg = m - s_mag[(ry + 1 - dy) * MG + (rx + 1 - dx)];
        float mf = (float)m;
        float thin = (fmin(pos, neg) > 0.0) ? mf : 0.f;
        size_t idx = ob + (size_t)(gy0 + ry) * W + (gx0 + rx);
        out_mag[idx]   = mf;
        out_ori[idx]   = q;
        out_thin[idx]  = thin;
        out_thr[idx]   = (thin < 10.f) ? 0.f : thin;
        out_early[idx] = (mf < 10.f) ? 0.f : mf;
    }
}

extern "C" void kernel_launch(void* const* d_in, const int* in_sizes, int n_in,
                              void* d_out, int out_size, void* d_ws, size_t ws_size,
                              hipStream_t stream) {
    const float* img   = (const float*)d_in[0];
    const float* gauss = (const float*)d_in[1];
    const int H = 1024, W = 1024;
    const int B = in_sizes[0] / (3 * H * W);

    float* out = (float*)d_out;
    const size_t cs = (size_t)H * W;
    float* out_blur  = out;
    float* out_mag   = out_blur + (size_t)B * 3 * cs;
    float* out_ori   = out_mag  + (size_t)B * cs;
    float* out_thin  = out_ori  + (size_t)B * cs;
    float* out_thr   = out_thin + (size_t)B * cs;
    float* out_early = out_thr  + (size_t)B * cs;

    dim3 grid(W / TILE, H / TILE, B);
    canny_fused_kernel<<<grid, NTHREADS, 0, stream>>>(
        img, gauss, out_blur, out_mag, out_ori, out_thin, out_thr, out_early, H, W);
}

// Round 4
// 101.861 us; speedup vs baseline: 1.6403x; 1.6403x over previous
//
#include <hip/hip_runtime.h>
#include <math.h>

#define TILE 32
#define RAW  40   // TILE + 2*4 halo
#define HBW  36   // RAW - 4 (after horizontal 5-tap)
#define VB   36   // 36x36 blurred region (rel coords -2..33)
#define MG   34   // 34x34 magnitude region (rel coords -1..32)
#define NTHREADS 256

__global__ __launch_bounds__(NTHREADS, 4) void canny_fused_kernel(
    const float* __restrict__ img,     // [B,3,H,W]
    const float* __restrict__ gauss,   // 5 floats (unnormalized gaussian)
    float* __restrict__ out_blur,      // [B,3,H,W]
    float* __restrict__ out_mag,       // [B,H,W]
    float* __restrict__ out_ori,
    float* __restrict__ out_thin,
    float* __restrict__ out_thr,
    float* __restrict__ out_early,
    int H, int W)
{
    // f64 decision chain (blur->sobel->mag->pos/neg, atan2 bins): round-2
    // showed full-f32 flips NMS decisions vs the numpy reference.
    // raw tile stays f32 (input values are exactly representable).
    __shared__ float  s_raw[RAW * RAW];
    __shared__ double s_hb [RAW * HBW];
    __shared__ double s_vb [VB * VB];
    __shared__ double s_mag[MG * MG];

    const int tid = threadIdx.x;
    const int b   = blockIdx.z;
    const int gy0 = blockIdx.y * TILE;
    const int gx0 = blockIdx.x * TILE;

    const double g0 = (double)gauss[0], g1 = (double)gauss[1], g2 = (double)gauss[2];

    for (int i = tid; i < MG * MG; i += NTHREADS) s_mag[i] = 0.0;

    // per-thread gx/gy accumulators for 4 owned core pixels (i = tid + 256p)
    double agx0 = 0.0, agx1 = 0.0, agx2 = 0.0, agx3 = 0.0;
    double agy0 = 0.0, agy1 = 0.0, agy2 = 0.0, agy3 = 0.0;

    const size_t cs = (size_t)H * W;

    for (int c = 0; c < 3; ++c) {
        __syncthreads();
        // ---- load raw 40x40 tile (zero-padded outside image) ----
        const float* ip = img + (size_t)(b * 3 + c) * cs;
        for (int i = tid; i < RAW * RAW; i += NTHREADS) {
            int ry = i / RAW, rx = i - ry * RAW;
            int y = gy0 + ry - 4, x = gx0 + rx - 4;
            float v = 0.f;
            if ((unsigned)y < (unsigned)H && (unsigned)x < (unsigned)W)
                v = ip[(size_t)y * W + x];
            s_raw[i] = v;
        }
        __syncthreads();
        // ---- horizontal 5-tap gaussian ----
        for (int i = tid; i < RAW * HBW; i += NTHREADS) {
            int y = i / HBW, xi = i - y * HBW;
            const float* r = s_raw + y * RAW + xi;
            s_hb[i] = g0 * (double)r[0] + g1 * (double)r[1] + g2 * (double)r[2]
                    + g1 * (double)r[3] + g0 * (double)r[4];
        }
        __syncthreads();
        // ---- vertical 5-tap gaussian, zeroed outside image (conv SAME pad) ----
        for (int i = tid; i < VB * VB; i += NTHREADS) {
            int yi = i / VB, xi = i - yi * VB;
            const double* h = s_hb + yi * HBW + xi;
            double v = g0 * h[0] + g1 * h[HBW] + g2 * h[2 * HBW] + g1 * h[3 * HBW] + g0 * h[4 * HBW];
            int y = gy0 + yi - 2, x = gx0 + xi - 2;
            if ((unsigned)y >= (unsigned)H || (unsigned)x >= (unsigned)W) v = 0.0;
            s_vb[i] = v;
        }
        __syncthreads();
        // ---- write blurred core (32x32) ----
        float* bp = out_blur + (size_t)(b * 3 + c) * cs;
        for (int i = tid; i < TILE * TILE; i += NTHREADS) {
            int ry = i >> 5, rx = i & 31;
            bp[(size_t)(gy0 + ry) * W + (gx0 + rx)] = (float)s_vb[(ry + 2) * VB + (rx + 2)];
        }
        // ---- sobel on vb -> accumulate mag over 34x34 ----
        for (int i = tid; i < MG * MG; i += NTHREADS) {
            int my = i / MG, mx = i - my * MG;   // center rel = (my-1, mx-1)
            const double* v = s_vb + my * VB + mx;
            double a00 = v[0],      a01 = v[1],          a02 = v[2];
            double a10 = v[VB],                          a12 = v[VB + 2];
            double a20 = v[2 * VB], a21 = v[2 * VB + 1], a22 = v[2 * VB + 2];
            double gx = (a00 - a02) + 2.0 * (a10 - a12) + (a20 - a22);
            double gy = (a00 - a20) + 2.0 * (a01 - a21) + (a02 - a22);
            int y = gy0 + my - 1, x = gx0 + mx - 1;
            if ((unsigned)y < (unsigned)H && (unsigned)x < (unsigned)W)
                s_mag[i] += sqrt(gx * gx + gy * gy);
        }
        // ---- sobel again for this thread's 4 core pixels -> register gx/gy ----
#pragma unroll 4
        for (int p = 0; p < 4; ++p) {
            int i = tid + p * NTHREADS;
            int ry = i >> 5, rx = i & 31;          // core rel coords, always in-image
            const double* v = s_vb + (ry + 1) * VB + (rx + 1);
            double a00 = v[0],      a01 = v[1],          a02 = v[2];
            double a10 = v[VB],                          a12 = v[VB + 2];
            double a20 = v[2 * VB], a21 = v[2 * VB + 1], a22 = v[2 * VB + 2];
            double gx = (a00 - a02) + 2.0 * (a10 - a12) + (a20 - a22);
            double gy = (a00 - a20) + 2.0 * (a01 - a21) + (a02 - a22);
            if (p == 0) { agx0 += gx; agy0 += gy; }
            else if (p == 1) { agx1 += gx; agy1 += gy; }
            else if (p == 2) { agx2 += gx; agy2 += gy; }
            else { agx3 += gx; agy3 += gy; }
        }
    }
    __syncthreads();

    // ---- orientation quantize + directional NMS + thresholds ----
    const size_t ob = (size_t)b * cs;
#pragma unroll 4
    for (int p = 0; p < 4; ++p) {
        int i = tid + p * NTHREADS;
        int ry = i >> 5, rx = i & 31;
        double gxv = (p == 0) ? agx0 : (p == 1) ? agx1 : (p == 2) ? agx2 : agx3;
        double gyv = (p == 0) ? agy0 : (p == 1) ? agy1 : (p == 2) ? agy2 : agy3;
        double m = s_mag[(ry + 1) * MG + (rx + 1)];
        double o = atan2(gyv, gxv) * 57.295827908797776;  // 180/3.14159
        int k = (int)rint((o + 180.0) / 45.0);            // 0..8, half-even
        float q = 45.f * (float)k;
        // Branch-cut hedge: at gy~0, gx<0 the reference's f32 noise decides
        // between 0 and 360 (diff 360 > threshold). Emit 180 (within 180 of
        // both). NMS unaffected: k=0 and k=8 alias mod 8.
        if (gxv < 0.0 && fabs(gyv) < 1e-2) q = 180.f;
        int kp = k & 7;
        // neighbor offsets, packed nibbles (value+1):
        // dy: k=0..7 -> 0,1,1,1,0,-1,-1,-1 ; dx: 1,1,0,-1,-1,-1,0,1
        int dy = (int)((0x00012221u >> (kp * 4)) & 7u) - 1;
        int dx = (int)((0x21000122u >> (kp * 4)) & 7u) - 1;
        double pos = m - s_mag[(ry + 1 + dy) * MG + (rx + 1 + dx)];
        double neg = m - s_mag[(ry + 1 - dy) * MG + (rx + 1 - dx)];
        float mf = (float)m;
        float thin = (fmin(pos, neg) > 0.0) ? mf : 0.f;
        size_t idx = ob + (size_t)(gy0 + ry) * W + (gx0 + rx);
        out_mag[idx]   = mf;
        out_ori[idx]   = q;
        out_thin[idx]  = thin;
        out_thr[idx]   = (thin < 10.f) ? 0.f : thin;
        out_early[idx] = (mf < 10.f) ? 0.f : mf;
    }
}

extern "C" void kernel_launch(void* const* d_in, const int* in_sizes, int n_in,
                              void* d_out, int out_size, void* d_ws, size_t ws_size,
                              hipStream_t stream) {
    const float* img   = (const float*)d_in[0];
    const float* gauss = (const float*)d_in[1];
    const int H = 1024, W = 1024;
    const int B = in_sizes[0] / (3 * H * W);

    float* out = (float*)d_out;
    const size_t cs = (size_t)H * W;
    float* out_blur  = out;
    float* out_mag   = out_blur + (size_t)B * 3 * cs;
    float* out_ori   = out_mag  + (size_t)B * cs;
    float* out_thin  = out_ori  + (size_t)B * cs;
    float* out_thr   = out_thin + (size_t)B * cs;
    float* out_early = out_thr  + (size_t)B * cs;

    dim3 grid(W / TILE, H / TILE, B);
    canny_fused_kernel<<<grid, NTHREADS, 0, stream>>>(
        img, gauss, out_blur, out_mag, out_ori, out_thin, out_thr, out_early, H, W);
}